// Round 18
// baseline (397.531 us; speedup 1.0000x reference)
//
#include <hip/hip_runtime.h>

// ---------- types / helpers ----------
typedef __attribute__((ext_vector_type(8))) short bfrag;   // 8 bf16 (4 VGPRs) MFMA operand
typedef __attribute__((ext_vector_type(4))) float f32x4;   // MFMA accumulator / NT-load vector

__device__ __forceinline__ float bf2f(unsigned short u) {
    union { unsigned u32; float f; } cv; cv.u32 = ((unsigned)u) << 16; return cv.f;
}
__device__ __forceinline__ unsigned short f2bf(float f) {
    union { float f; unsigned u; } cv; cv.f = f;
    unsigned u = cv.u;
    unsigned r = (u + 0x7fffu + ((u >> 16) & 1u)) >> 16;   // round-to-nearest-even
    return (unsigned short)r;
}
__device__ __forceinline__ void gll16(const void* g, void* l) {
    __builtin_amdgcn_global_load_lds(
        (const __attribute__((address_space(1))) unsigned int*)g,
        (__attribute__((address_space(3))) unsigned int*)l, 16, 0, 0);
}

// ---------- f32 -> bf16 bulk convert (NT loads) ----------
__global__ void to_bf16(const float* __restrict__ src, unsigned short* __restrict__ dst, size_t n) {
    size_t i = ((size_t)blockIdx.x * 256 + threadIdx.x) * 8;
    if (i >= n) return;
    f32x4 a = __builtin_nontemporal_load(reinterpret_cast<const f32x4*>(src + i));
    f32x4 b = __builtin_nontemporal_load(reinterpret_cast<const f32x4*>(src + i + 4));
    ushort4 o0 = {f2bf(a.x), f2bf(a.y), f2bf(a.z), f2bf(a.w)};
    ushort4 o1 = {f2bf(b.x), f2bf(b.y), f2bf(b.z), f2bf(b.w)};
    *reinterpret_cast<ushort4*>(dst + i) = o0;
    *reinterpret_cast<ushort4*>(dst + i + 4) = o1;
}

// ---------- weight transpose + pad + bf16 convert with K-permutation ----------
__global__ void transpose_pad(const float* __restrict__ W, unsigned short* __restrict__ WT,
                              int R, int Cn, int Kp, int split, int shiftA, int split2, int shiftB) {
    __shared__ unsigned short tile[32][33];
    int r0 = blockIdx.x * 32, c0 = blockIdx.y * 32;
#pragma unroll
    for (int j = 0; j < 4; j++) {
        int r = r0 + threadIdx.y + j * 8;
        int c = c0 + threadIdx.x;
        float v = (r < R) ? W[(size_t)r * Cn + c] : 0.f;
        tile[threadIdx.y + j * 8][threadIdx.x] = f2bf(v);
    }
    __syncthreads();
#pragma unroll
    for (int j = 0; j < 4; j++) {
        int c = c0 + threadIdx.y + j * 8;
        int r = r0 + threadIdx.x;
        int kn = (r < split) ? r + shiftA : (r < split2 ? r + shiftB : r);
        WT[(size_t)c * Kp + kn] = tile[threadIdx.x][threadIdx.y + j * 8];
    }
}

// ---------- gather-sum + concat, FULL wave per row (r15/r17-verified) ----------
__global__ __launch_bounds__(256) void gather2(const unsigned short* __restrict__ abf,
                                               const float* __restrict__ f_atoms,
                                               const int* __restrict__ a2a,
                                               unsigned short* __restrict__ xb, int n_real) {
    int r = blockIdx.x * 4 + (threadIdx.x >> 6);
    int lane = threadIdx.x & 63;
    unsigned short* xrow = xb + (size_t)r * 448;
    if (r >= n_real) {
        *reinterpret_cast<ushort4*>(xrow + lane * 4) = ushort4{0, 0, 0, 0};
        if (lane < 48) *reinterpret_cast<ushort4*>(xrow + 256 + lane * 4) = ushort4{0, 0, 0, 0};
        return;
    }
    int v = (lane < 10) ? a2a[(size_t)r * 10 + lane] : 0;
    ushort4 u[10];
#pragma unroll
    for (int j = 0; j < 10; j++) {
        int nbj = __shfl(v, j);
        u[j] = *reinterpret_cast<const ushort4*>(abf + (size_t)nbj * 256 + lane * 4);
    }
    float a0 = 0.f, a1 = 0.f, a2 = 0.f, a3 = 0.f;
#pragma unroll
    for (int j = 0; j < 10; j++) {
        a0 += bf2f(u[j].x);
        a1 += bf2f(u[j].y);
        a2 += bf2f(u[j].z);
        a3 += bf2f(u[j].w);
    }
    ushort4 o = {f2bf(a0), f2bf(a1), f2bf(a2), f2bf(a3)};
    *reinterpret_cast<ushort4*>(xrow + lane * 4) = o;   // aggr -> cols 0..255
    const float* fr = f_atoms + (size_t)r * 151;
#pragma unroll
    for (int s = 0; s < 3; s++) {
        int c = lane + s * 64;
        if (c < 151) xrow[256 + c] = f2bf(__builtin_nontemporal_load(fr + c));
    }
    if (lane < 41) xrow[407 + lane] = 0;
}

// ---------- PIPELINED gemm1: 256x128, BK=32, double-buffered 48 KB, counted vmcnt ----------
// Same occupancy as r12 (48 KB -> 3 blocks/CU) but staging stays in flight across iters:
// ledger: prologue stages tile0+tile1 (6 gll16); per iter vmcnt(3) = tile t landed, t+1 flying;
// stage t+2 after the read-barrier into the freed buffer. Last iter vmcnt(0).
// 4-slot row swizzle: LDS[row][s] holds k-chunk (s - ((row>>1)&3))&3; reader s=(hi+((la>>1)&3))&3
// -> 2 lanes/bank worst case (free, m136). relu fused.
__global__ __launch_bounds__(512, 2) void gemm1p(const unsigned short* __restrict__ A,
                                                 const unsigned short* __restrict__ BT,
                                                 const float* __restrict__ bias,
                                                 unsigned short* __restrict__ C,
                                                 int NB, int N, int K) {
    __shared__ __align__(16) unsigned short As[2][256 * 32];   // 32 KB
    __shared__ __align__(16) unsigned short Bs[2][128 * 32];   // 16 KB
    const int t = threadIdx.x;
    const int lane = t & 63, wid = t >> 6;
    const int wm = wid >> 1, wn = wid & 1;
    const int la = lane & 15, hi = lane >> 4;

    const int nwg = gridDim.x, orig = blockIdx.x;
    const int q = nwg >> 3, r8 = nwg & 7;
    const int xcd = orig & 7, slot = orig >> 3;
    const int wgid = (xcd < r8 ? xcd * (q + 1) : r8 * (q + 1) + (xcd - r8) * q) + slot;
    const int bm = (wgid / NB) * 256, bn = (wgid % NB) * 128;

    f32x4 acc[4][4] = {};

    // staging map: thread t -> row tr = t>>2 (per 128-row sweep), 16B slot ts = t&3
    const int tr = t >> 2, ts = t & 3;
    const int koff = ((ts - ((tr >> 1) & 3)) & 3) * 8;   // inverse of read swizzle
    const unsigned short* Ag = A + (size_t)(bm + tr) * K + koff;
    const unsigned short* Bg = BT + (size_t)(bn + tr) * K + koff;
    const int ldst = tr * 32 + ts * 8;

    auto stage = [&](int buf, int kt) {
        gll16(Ag + kt, &As[buf][ldst]);
        gll16(Ag + (size_t)128 * K + kt, &As[buf][4096 + ldst]);
        gll16(Bg + kt, &Bs[buf][ldst]);
    };

    const int NT = K >> 5;
    stage(0, 0);
    stage(1, 32);

    const int slotOff = ((hi + ((la >> 1) & 3)) & 3) * 8;   // read-side swizzle (row-indep, see derivation)
    int cur = 0;
    for (int it = 0; it < NT; ++it) {
        if (it + 1 < NT) asm volatile("s_waitcnt vmcnt(3)" ::: "memory");   // tile it landed
        else             asm volatile("s_waitcnt vmcnt(0)" ::: "memory");
        __builtin_amdgcn_s_barrier();   // every wave's stage ops landed -> whole tile valid
        bfrag a[4], b[4];
#pragma unroll
        for (int i = 0; i < 4; i++)
            a[i] = *reinterpret_cast<const bfrag*>(&As[cur][(wm * 64 + i * 16 + la) * 32 + slotOff]);
#pragma unroll
        for (int j = 0; j < 4; j++)
            b[j] = *reinterpret_cast<const bfrag*>(&Bs[cur][(wn * 64 + j * 16 + la) * 32 + slotOff]);
#pragma unroll
        for (int i = 0; i < 4; i++)
#pragma unroll
            for (int j = 0; j < 4; j++)
                acc[i][j] = __builtin_amdgcn_mfma_f32_16x16x32_bf16(a[i], b[j], acc[i][j], 0, 0, 0);
        __builtin_amdgcn_s_barrier();   // all waves consumed buf[cur] -> safe to overwrite
        if (it + 2 < NT) stage(cur, (it + 2) * 32);
        cur ^= 1;
    }

    // epilogue (r12-verified, coalesced: col = lane&15)
#pragma unroll
    for (int j = 0; j < 4; j++) {
        int col = bn + wn * 64 + j * 16 + la;
        float bv = bias[col];
#pragma unroll
        for (int i = 0; i < 4; i++) {
            int rbase = bm + wm * 64 + i * 16 + hi * 4;
#pragma unroll
            for (int r = 0; r < 4; r++) {
                float v = fmaxf(acc[i][j][r] + bv, 0.f);
                C[(size_t)(rbase + r) * N + col] = f2bf(v);
            }
        }
    }
}

// ---------- 256x128 bf16 MFMA GEMM (r12 byte-exact, used for gemm3) ----------
template <int RELU>
__global__ __launch_bounds__(512, 2) void gemm256(const unsigned short* __restrict__ A,
                                                  const unsigned short* __restrict__ BT,
                                                  const float* __restrict__ bias,
                                                  unsigned short* __restrict__ C,
                                                  int NB, int N, int K) {
    __shared__ __align__(16) unsigned short As[256 * 64];   // 32 KB
    __shared__ __align__(16) unsigned short Bs[128 * 64];   // 16 KB
    const int t = threadIdx.x;
    const int lane = t & 63, wid = t >> 6;
    const int wm = wid >> 1, wn = wid & 1;
    const int la = lane & 15, hi = lane >> 4;

    const int nwg = gridDim.x, orig = blockIdx.x;
    const int q = nwg >> 3, r8 = nwg & 7;
    const int xcd = orig & 7, slot = orig >> 3;
    const int wgid = (xcd < r8 ? xcd * (q + 1) : r8 * (q + 1) + (xcd - r8) * q) + slot;
    const int bm = (wgid / NB) * 256, bn = (wgid % NB) * 128;

    f32x4 acc[4][4] = {};

    const int tr = t >> 3, ts = t & 7;
    const unsigned short* Ag = A + (size_t)(bm + tr) * K + (ts ^ (tr & 7)) * 8;
    const unsigned short* Bg = BT + (size_t)(bn + tr) * K + (ts ^ (tr & 7)) * 8;
    const int ldst = tr * 64 + ts * 8;

    for (int kt = 0; kt < K; kt += 64) {
        __builtin_amdgcn_s_barrier();
#pragma unroll
        for (int p = 0; p < 4; p++) gll16(Ag + (size_t)(p * 64) * K + kt, &As[p * 4096 + ldst]);
#pragma unroll
        for (int p = 0; p < 2; p++) gll16(Bg + (size_t)(p * 64) * K + kt, &Bs[p * 4096 + ldst]);
        asm volatile("s_waitcnt vmcnt(0)" ::: "memory");
        __builtin_amdgcn_s_barrier();
#pragma unroll
        for (int kk = 0; kk < 2; kk++) {
            bfrag a[4], b[4];
#pragma unroll
            for (int i = 0; i < 4; i++) {
                int row = wm * 64 + i * 16 + la;
                a[i] = *reinterpret_cast<const bfrag*>(&As[row * 64 + (((kk * 4 + hi) ^ (la & 7)) * 8)]);
            }
#pragma unroll
            for (int j = 0; j < 4; j++) {
                int row = wn * 64 + j * 16 + la;
                b[j] = *reinterpret_cast<const bfrag*>(&Bs[row * 64 + (((kk * 4 + hi) ^ (la & 7)) * 8)]);
            }
#pragma unroll
            for (int i = 0; i < 4; i++)
#pragma unroll
                for (int j = 0; j < 4; j++)
                    acc[i][j] = __builtin_amdgcn_mfma_f32_16x16x32_bf16(a[i], b[j], acc[i][j], 0, 0, 0);
        }
    }

#pragma unroll
    for (int j = 0; j < 4; j++) {
        int col = bn + wn * 64 + j * 16 + la;
        float bv = bias[col];
#pragma unroll
        for (int i = 0; i < 4; i++) {
            int rbase = bm + wm * 64 + i * 16 + hi * 4;
#pragma unroll
            for (int r = 0; r < 4; r++) {
                float v = acc[i][j][r] + bv;
                if (RELU) v = fmaxf(v, 0.f);
                C[(size_t)(rbase + r) * N + col] = f2bf(v);
            }
        }
    }
}

// ---------- standalone gemm2: 128x256 tile, NB=1 (h1 staged exactly once) ----------
__global__ __launch_bounds__(512, 2) void gemm2k(const unsigned short* __restrict__ A,
                                                 const unsigned short* __restrict__ BT,
                                                 const float* __restrict__ bias,
                                                 unsigned short* __restrict__ C, int K) {
    __shared__ __align__(16) unsigned short As[128 * 64];   // 16 KB
    __shared__ __align__(16) unsigned short Bs[256 * 64];   // 32 KB
    const int t = threadIdx.x;
    const int lane = t & 63, wid = t >> 6;
    const int wm = wid >> 2, wn = wid & 3;
    const int la = lane & 15, hi = lane >> 4;
    const int N = 256;

    const int nwg = gridDim.x, orig = blockIdx.x;
    const int q = nwg >> 3, r8 = nwg & 7;
    const int xcd = orig & 7, slot = orig >> 3;
    const int wgid = (xcd < r8 ? xcd * (q + 1) : r8 * (q + 1) + (xcd - r8) * q) + slot;
    const int bm = wgid * 128;

    f32x4 acc[4][4] = {};

    const int tr = t >> 3, ts = t & 7;
    const unsigned short* Ag = A + (size_t)(bm + tr) * K + (ts ^ (tr & 7)) * 8;
    const unsigned short* Bg = BT + (size_t)tr * K + (ts ^ (tr & 7)) * 8;
    const int ldst = tr * 64 + ts * 8;

    for (int kt = 0; kt < K; kt += 64) {
        __builtin_amdgcn_s_barrier();
#pragma unroll
        for (int p = 0; p < 2; p++) gll16(Ag + (size_t)(p * 64) * K + kt, &As[p * 4096 + ldst]);
#pragma unroll
        for (int p = 0; p < 4; p++) gll16(Bg + (size_t)(p * 64) * K + kt, &Bs[p * 4096 + ldst]);
        asm volatile("s_waitcnt vmcnt(0)" ::: "memory");
        __builtin_amdgcn_s_barrier();
#pragma unroll
        for (int kk = 0; kk < 2; kk++) {
            bfrag a[4], b[4];
#pragma unroll
            for (int i = 0; i < 4; i++) {
                int row = wm * 64 + i * 16 + la;
                a[i] = *reinterpret_cast<const bfrag*>(&As[row * 64 + (((kk * 4 + hi) ^ (la & 7)) * 8)]);
            }
#pragma unroll
            for (int j = 0; j < 4; j++) {
                int row = wn * 64 + j * 16 + la;
                b[j] = *reinterpret_cast<const bfrag*>(&Bs[row * 64 + (((kk * 4 + hi) ^ (la & 7)) * 8)]);
            }
#pragma unroll
            for (int i = 0; i < 4; i++)
#pragma unroll
                for (int j = 0; j < 4; j++)
                    acc[i][j] = __builtin_amdgcn_mfma_f32_16x16x32_bf16(a[i], b[j], acc[i][j], 0, 0, 0);
        }
    }

#pragma unroll
    for (int j = 0; j < 4; j++) {
        int col = wn * 64 + j * 16 + la;
        float bv = bias[col];
#pragma unroll
        for (int i = 0; i < 4; i++) {
            int rbase = bm + wm * 64 + i * 16 + hi * 4;
#pragma unroll
            for (int r = 0; r < 4; r++)
                C[(size_t)(rbase + r) * N + col] = f2bf(acc[i][j][r] + bv);
        }
    }
}

// ---------- fused LayerNorm + segment-mean + feature concat ----------
__global__ __launch_bounds__(512) void seg_ln_mean(const unsigned short* __restrict__ h,
                                                   const int* __restrict__ a_scope,
                                                   const float* __restrict__ g,
                                                   const float* __restrict__ b,
                                                   const float* __restrict__ feats,
                                                   unsigned short* __restrict__ mol, int n_mols) {
    __shared__ float part[8][256];
    int m = blockIdx.x, t = threadIdx.x;
    unsigned short* mrow = mol + (size_t)m * 512;
    if (m >= n_mols) {
        mrow[t] = 0;
        return;
    }
    int w = t >> 6, lane = t & 63;
    int start = a_scope[2 * m], size = a_scope[2 * m + 1];
    float4 gv = *reinterpret_cast<const float4*>(g + lane * 4);
    float4 bv = *reinterpret_cast<const float4*>(b + lane * 4);
    float a0 = 0.f, a1 = 0.f, a2 = 0.f, a3 = 0.f;
    for (int r = w; r < size; r += 8) {
        const unsigned short* hp = h + (size_t)(start + r) * 256 + lane * 4;
        ushort4 u = *reinterpret_cast<const ushort4*>(hp);
        float v0 = bf2f(u.x), v1 = bf2f(u.y), v2 = bf2f(u.z), v3 = bf2f(u.w);
        float s = v0 + v1 + v2 + v3;
        float q2 = v0 * v0 + v1 * v1 + v2 * v2 + v3 * v3;
#pragma unroll
        for (int off = 32; off; off >>= 1) {
            s += __shfl_xor(s, off);
            q2 += __shfl_xor(q2, off);
        }
        float mean = s * (1.f / 256.f);
        float var = q2 * (1.f / 256.f) - mean * mean;
        float rs = rsqrtf(var + 1e-5f);
        a0 += (v0 - mean) * rs * gv.x + bv.x;
        a1 += (v1 - mean) * rs * gv.y + bv.y;
        a2 += (v2 - mean) * rs * gv.z + bv.z;
        a3 += (v3 - mean) * rs * gv.w + bv.w;
    }
    part[w][lane * 4 + 0] = a0;
    part[w][lane * 4 + 1] = a1;
    part[w][lane * 4 + 2] = a2;
    part[w][lane * 4 + 3] = a3;
    __syncthreads();
    if (t < 256) {
        float sum = 0.f;
#pragma unroll
        for (int i = 0; i < 8; i++) sum += part[i][t];
        mrow[t] = f2bf(sum / (float)size);
    } else {
        int c = t - 256;
        float fv = (c < 200) ? feats[(size_t)m * 200 + c] : 0.f;
        mrow[256 + c] = f2bf(fv);
    }
}

// ---------- final tiny FFN layer ----------
__global__ void ffn2(const unsigned short* __restrict__ m1, const float* __restrict__ Wm2,
                     const float* __restrict__ bm2, float* __restrict__ out, int n_mols) {
    int wid = blockIdx.x * 4 + (threadIdx.x >> 6);
    if (wid >= n_mols) return;
    int lane = threadIdx.x & 63;
    float acc[12] = {};
    const unsigned short* row = m1 + (size_t)wid * 1024;
#pragma unroll 4
    for (int i = 0; i < 16; i++) {
        int k = i * 64 + lane;
        float v = bf2f(row[k]);
        const float* wr_ = Wm2 + (size_t)k * 12;
#pragma unroll
        for (int tsk = 0; tsk < 12; tsk++) acc[tsk] += v * wr_[tsk];
    }
#pragma unroll
    for (int tsk = 0; tsk < 12; tsk++) {
        float sv = acc[tsk];
#pragma unroll
        for (int off = 32; off; off >>= 1) sv += __shfl_xor(sv, off);
        if (lane == 0) out[(size_t)wid * 12 + tsk] = sv + bm2[tsk];
    }
}

// ---------- launch ----------
extern "C" void kernel_launch(void* const* d_in, const int* in_sizes, int n_in,
                              void* d_out, int out_size, void* d_ws, size_t ws_size,
                              hipStream_t stream) {
    const float* atom_output = (const float*)d_in[0];
    const float* f_atoms     = (const float*)d_in[1];
    const int*   a2a         = (const int*)d_in[2];
    const int*   a_scope     = (const int*)d_in[3];
    const float* feats       = (const float*)d_in[4];
    const float* W1  = (const float*)d_in[5];
    const float* b1  = (const float*)d_in[6];
    const float* W2  = (const float*)d_in[7];
    const float* b2  = (const float*)d_in[8];
    const float* ln_g = (const float*)d_in[9];
    const float* ln_b = (const float*)d_in[10];
    const float* Wm1 = (const float*)d_in[11];
    const float* bm1 = (const float*)d_in[12];
    const float* Wm2 = (const float*)d_in[13];
    const float* bm2 = (const float*)d_in[14];
    float* out = (float*)d_out;

    char* ws = (char*)d_ws;
    size_t off = 0;
    auto alloc = [&](size_t bytes) {
        void* p = ws + off;
        off += (bytes + 255) & ~(size_t)255;
        return p;
    };
    // r12 layout (~356 MB). abf aliases h1 (dead before gemm1 writes h1).
    unsigned short* h     = (unsigned short*)alloc((size_t)100096 * 256 * 2);    // 51.2 MB
    unsigned short* h1    = (unsigned short*)alloc((size_t)100096 * 1024 * 2);   // 205.0 MB
    unsigned short* xf    = (unsigned short*)alloc((size_t)100096 * 448 * 2);    // 89.7 MB
    unsigned short* mol   = (unsigned short*)alloc((size_t)2560 * 512 * 2);
    unsigned short* m1b   = (unsigned short*)alloc((size_t)2560 * 1024 * 2);
    unsigned short* W1bT  = (unsigned short*)alloc((size_t)1024 * 448 * 2);
    unsigned short* W2bT  = (unsigned short*)alloc((size_t)256 * 1024 * 2);
    unsigned short* Wm1bT = (unsigned short*)alloc((size_t)1024 * 512 * 2);
    unsigned short* abf   = h1;   // alias: consumed by gather2 before h1 is written

    // weight prep. W1 K-permuted for x = [aggr | f_atoms | pad]
    transpose_pad<<<dim3(14, 32), dim3(32, 8), 0, stream>>>(W1, W1bT, 407, 1024, 448, 151, 256, 407, -151);
    transpose_pad<<<dim3(32, 8),  dim3(32, 8), 0, stream>>>(W2, W2bT, 1024, 256, 1024, 0, 0, 0, 0);
    transpose_pad<<<dim3(16, 32), dim3(32, 8), 0, stream>>>(Wm1, Wm1bT, 456, 1024, 512, 0, 0, 0, 0);

    to_bf16<<<12500, 256, 0, stream>>>(atom_output, abf, (size_t)100000 * 256);
    gather2<<<25024, 256, 0, stream>>>(abf, f_atoms, a2a, xf, 100000);

    // h1 = relu(x @ W1 + b1) : M=100096 (391x256), N=1024, K=448 ; PIPELINED BK=32 dbuf kernel
    gemm1p<<<391 * 8, 512, 0, stream>>>(xf, W1bT, b1, h1, 8, 1024, 448);
    // h = h1 @ W2 + b2 : M=100096 (782x128), N=256, K=1024 ; NB=1 -> h1 staged ONCE
    gemm2k<<<782, 512, 0, stream>>>(h1, W2bT, b2, h, 1024);

    seg_ln_mean<<<2560, 512, 0, stream>>>(h, a_scope, ln_g, ln_b, feats, mol, 2500);
    // m1 = relu(mol @ Wm1 + bm1) : M=2560 (10x256), N=1024, K=512
    gemm256<1><<<10 * 8, 512, 0, stream>>>(mol, Wm1bT, bm1, m1b, 8, 1024, 512);
    ffn2<<<625, 256, 0, stream>>>(m1b, Wm2, bm2, out, 2500);
}

// Round 19
// 385.737 us; speedup vs baseline: 1.0306x; 1.0306x over previous
//
#include <hip/hip_runtime.h>

// ---------- types / helpers ----------
typedef __attribute__((ext_vector_type(8))) short bfrag;   // 8 bf16 (4 VGPRs) MFMA operand
typedef __attribute__((ext_vector_type(4))) float f32x4;   // MFMA accumulator / NT-load vector

__device__ __forceinline__ float bf2f(unsigned short u) {
    union { unsigned u32; float f; } cv; cv.u32 = ((unsigned)u) << 16; return cv.f;
}
__device__ __forceinline__ unsigned short f2bf(float f) {
    union { float f; unsigned u; } cv; cv.f = f;
    unsigned u = cv.u;
    unsigned r = (u + 0x7fffu + ((u >> 16) & 1u)) >> 16;   // round-to-nearest-even
    return (unsigned short)r;
}
__device__ __forceinline__ void gll16(const void* g, void* l) {
    __builtin_amdgcn_global_load_lds(
        (const __attribute__((address_space(1))) unsigned int*)g,
        (__attribute__((address_space(3))) unsigned int*)l, 16, 0, 0);
}

// ---------- fused prep: to_bf16 (atom_output) + 3x transpose_pad, ONE dispatch ----------
// HIP stream kernels serialize completion; merging 4 tiny prep launches removes 3 launch/ramp
// boundaries (~10-15 us under graph replay). Block ranges: [0,12500) convert, then W1/W2/Wm1.
__global__ __launch_bounds__(256) void prep(const float* __restrict__ atom_output,
                                            unsigned short* __restrict__ abf,
                                            const float* __restrict__ W1, unsigned short* __restrict__ W1bT,
                                            const float* __restrict__ W2, unsigned short* __restrict__ W2bT,
                                            const float* __restrict__ Wm1, unsigned short* __restrict__ Wm1bT) {
    __shared__ unsigned short tile[32][33];
    int bid = blockIdx.x;
    const int tx = threadIdx.x, ty = threadIdx.y;   // block = (32,8)
    if (bid < 12500) {
        // to_bf16: 25.6e6 elements, 8/thread (exact, no guard)
        size_t i = ((size_t)bid * 256 + ty * 32 + tx) * 8;
        f32x4 a = __builtin_nontemporal_load(reinterpret_cast<const f32x4*>(atom_output + i));
        f32x4 b = __builtin_nontemporal_load(reinterpret_cast<const f32x4*>(atom_output + i + 4));
        ushort4 o0 = {f2bf(a.x), f2bf(a.y), f2bf(a.z), f2bf(a.w)};
        ushort4 o1 = {f2bf(b.x), f2bf(b.y), f2bf(b.z), f2bf(b.w)};
        *reinterpret_cast<ushort4*>(abf + i) = o0;
        *reinterpret_cast<ushort4*>(abf + i + 4) = o1;
        return;
    }
    bid -= 12500;
    const float* W; unsigned short* WT;
    int R, Cn, Kp, split, shiftA, split2, shiftB, bx, by;
    if (bid < 448) {          // W1: grid (14,32), K-permuted for x = [aggr | f_atoms | pad]
        W = W1; WT = W1bT; R = 407; Cn = 1024; Kp = 448;
        split = 151; shiftA = 256; split2 = 407; shiftB = -151;
        bx = bid % 14; by = bid / 14;
    } else if (bid < 704) {   // W2: grid (32,8)
        bid -= 448;
        W = W2; WT = W2bT; R = 1024; Cn = 256; Kp = 1024;
        split = 0; shiftA = 0; split2 = 0; shiftB = 0;
        bx = bid % 32; by = bid / 32;
    } else {                  // Wm1: grid (16,32)
        bid -= 704;
        W = Wm1; WT = Wm1bT; R = 456; Cn = 1024; Kp = 512;
        split = 0; shiftA = 0; split2 = 0; shiftB = 0;
        bx = bid % 16; by = bid / 16;
    }
    int r0 = bx * 32, c0 = by * 32;
#pragma unroll
    for (int j = 0; j < 4; j++) {
        int r = r0 + ty + j * 8;
        int c = c0 + tx;
        float v = (r < R) ? W[(size_t)r * Cn + c] : 0.f;
        tile[ty + j * 8][tx] = f2bf(v);
    }
    __syncthreads();
#pragma unroll
    for (int j = 0; j < 4; j++) {
        int c = c0 + ty + j * 8;
        int r = r0 + tx;
        int kn = (r < split) ? r + shiftA : (r < split2 ? r + shiftB : r);
        WT[(size_t)c * Kp + kn] = tile[tx][ty + j * 8];
    }
}

// ---------- gather-sum + concat, FULL wave per row (r15/r17-verified) ----------
__global__ __launch_bounds__(256) void gather2(const unsigned short* __restrict__ abf,
                                               const float* __restrict__ f_atoms,
                                               const int* __restrict__ a2a,
                                               unsigned short* __restrict__ xb, int n_real) {
    int r = blockIdx.x * 4 + (threadIdx.x >> 6);
    int lane = threadIdx.x & 63;
    unsigned short* xrow = xb + (size_t)r * 448;
    if (r >= n_real) {
        *reinterpret_cast<ushort4*>(xrow + lane * 4) = ushort4{0, 0, 0, 0};
        if (lane < 48) *reinterpret_cast<ushort4*>(xrow + 256 + lane * 4) = ushort4{0, 0, 0, 0};
        return;
    }
    int v = (lane < 10) ? a2a[(size_t)r * 10 + lane] : 0;
    ushort4 u[10];
#pragma unroll
    for (int j = 0; j < 10; j++) {
        int nbj = __shfl(v, j);
        u[j] = *reinterpret_cast<const ushort4*>(abf + (size_t)nbj * 256 + lane * 4);
    }
    float a0 = 0.f, a1 = 0.f, a2 = 0.f, a3 = 0.f;
#pragma unroll
    for (int j = 0; j < 10; j++) {
        a0 += bf2f(u[j].x);
        a1 += bf2f(u[j].y);
        a2 += bf2f(u[j].z);
        a3 += bf2f(u[j].w);
    }
    ushort4 o = {f2bf(a0), f2bf(a1), f2bf(a2), f2bf(a3)};
    *reinterpret_cast<ushort4*>(xrow + lane * 4) = o;   // aggr -> cols 0..255
    const float* fr = f_atoms + (size_t)r * 151;
#pragma unroll
    for (int s = 0; s < 3; s++) {
        int c = lane + s * 64;
        if (c < 151) xrow[256 + c] = f2bf(__builtin_nontemporal_load(fr + c));
    }
    if (lane < 41) xrow[407 + lane] = 0;
}

// ---------- 256x128 bf16 MFMA GEMM (r12 byte-exact): C = A*BT^T (+bias, relu) ----------
// 8 waves (4M x 2N), wave tile 64x64, BK=64, single 48 KB LDS (3 blocks/CU), XOR slot<->row
// swizzle, bijective XCD swizzle, coalesced epilogue. r12/r17-verified: 146 us, MfmaUtil ~26%.
// Structural note: 6 schedule variants (dbuf/8-phase/wide-N/chunk/NT/BK32-pipe) all lost to
// this form — at K=448 the loop is per-iteration-latency bound; co-residency is the overlap.
template <int RELU>
__global__ __launch_bounds__(512, 2) void gemm256(const unsigned short* __restrict__ A,
                                                  const unsigned short* __restrict__ BT,
                                                  const float* __restrict__ bias,
                                                  unsigned short* __restrict__ C,
                                                  int NB, int N, int K) {
    __shared__ __align__(16) unsigned short As[256 * 64];   // 32 KB
    __shared__ __align__(16) unsigned short Bs[128 * 64];   // 16 KB
    const int t = threadIdx.x;
    const int lane = t & 63, wid = t >> 6;
    const int wm = wid >> 1, wn = wid & 1;
    const int la = lane & 15, hi = lane >> 4;

    const int nwg = gridDim.x, orig = blockIdx.x;
    const int q = nwg >> 3, r8 = nwg & 7;
    const int xcd = orig & 7, slot = orig >> 3;
    const int wgid = (xcd < r8 ? xcd * (q + 1) : r8 * (q + 1) + (xcd - r8) * q) + slot;
    const int bm = (wgid / NB) * 256, bn = (wgid % NB) * 128;

    f32x4 acc[4][4] = {};

    const int tr = t >> 3, ts = t & 7;
    const unsigned short* Ag = A + (size_t)(bm + tr) * K + (ts ^ (tr & 7)) * 8;
    const unsigned short* Bg = BT + (size_t)(bn + tr) * K + (ts ^ (tr & 7)) * 8;
    const int ldst = tr * 64 + ts * 8;

    for (int kt = 0; kt < K; kt += 64) {
        __builtin_amdgcn_s_barrier();
#pragma unroll
        for (int p = 0; p < 4; p++) gll16(Ag + (size_t)(p * 64) * K + kt, &As[p * 4096 + ldst]);
#pragma unroll
        for (int p = 0; p < 2; p++) gll16(Bg + (size_t)(p * 64) * K + kt, &Bs[p * 4096 + ldst]);
        asm volatile("s_waitcnt vmcnt(0)" ::: "memory");
        __builtin_amdgcn_s_barrier();
#pragma unroll
        for (int kk = 0; kk < 2; kk++) {
            bfrag a[4], b[4];
#pragma unroll
            for (int i = 0; i < 4; i++) {
                int row = wm * 64 + i * 16 + la;
                a[i] = *reinterpret_cast<const bfrag*>(&As[row * 64 + (((kk * 4 + hi) ^ (la & 7)) * 8)]);
            }
#pragma unroll
            for (int j = 0; j < 4; j++) {
                int row = wn * 64 + j * 16 + la;
                b[j] = *reinterpret_cast<const bfrag*>(&Bs[row * 64 + (((kk * 4 + hi) ^ (la & 7)) * 8)]);
            }
#pragma unroll
            for (int i = 0; i < 4; i++)
#pragma unroll
                for (int j = 0; j < 4; j++)
                    acc[i][j] = __builtin_amdgcn_mfma_f32_16x16x32_bf16(a[i], b[j], acc[i][j], 0, 0, 0);
        }
    }

#pragma unroll
    for (int j = 0; j < 4; j++) {
        int col = bn + wn * 64 + j * 16 + la;
        float bv = bias[col];
#pragma unroll
        for (int i = 0; i < 4; i++) {
            int rbase = bm + wm * 64 + i * 16 + hi * 4;
#pragma unroll
            for (int r = 0; r < 4; r++) {
                float v = acc[i][j][r] + bv;
                if (RELU) v = fmaxf(v, 0.f);
                C[(size_t)(rbase + r) * N + col] = f2bf(v);
            }
        }
    }
}

// ---------- standalone gemm2: 128x256 tile, NB=1 (h1 staged exactly once) ----------
__global__ __launch_bounds__(512, 2) void gemm2k(const unsigned short* __restrict__ A,
                                                 const unsigned short* __restrict__ BT,
                                                 const float* __restrict__ bias,
                                                 unsigned short* __restrict__ C, int K) {
    __shared__ __align__(16) unsigned short As[128 * 64];   // 16 KB
    __shared__ __align__(16) unsigned short Bs[256 * 64];   // 32 KB
    const int t = threadIdx.x;
    const int lane = t & 63, wid = t >> 6;
    const int wm = wid >> 2, wn = wid & 3;
    const int la = lane & 15, hi = lane >> 4;
    const int N = 256;

    const int nwg = gridDim.x, orig = blockIdx.x;
    const int q = nwg >> 3, r8 = nwg & 7;
    const int xcd = orig & 7, slot = orig >> 3;
    const int wgid = (xcd < r8 ? xcd * (q + 1) : r8 * (q + 1) + (xcd - r8) * q) + slot;
    const int bm = wgid * 128;

    f32x4 acc[4][4] = {};

    const int tr = t >> 3, ts = t & 7;
    const unsigned short* Ag = A + (size_t)(bm + tr) * K + (ts ^ (tr & 7)) * 8;
    const unsigned short* Bg = BT + (size_t)tr * K + (ts ^ (tr & 7)) * 8;
    const int ldst = tr * 64 + ts * 8;

    for (int kt = 0; kt < K; kt += 64) {
        __builtin_amdgcn_s_barrier();
#pragma unroll
        for (int p = 0; p < 2; p++) gll16(Ag + (size_t)(p * 64) * K + kt, &As[p * 4096 + ldst]);
#pragma unroll
        for (int p = 0; p < 4; p++) gll16(Bg + (size_t)(p * 64) * K + kt, &Bs[p * 4096 + ldst]);
        asm volatile("s_waitcnt vmcnt(0)" ::: "memory");
        __builtin_amdgcn_s_barrier();
#pragma unroll
        for (int kk = 0; kk < 2; kk++) {
            bfrag a[4], b[4];
#pragma unroll
            for (int i = 0; i < 4; i++) {
                int row = wm * 64 + i * 16 + la;
                a[i] = *reinterpret_cast<const bfrag*>(&As[row * 64 + (((kk * 4 + hi) ^ (la & 7)) * 8)]);
            }
#pragma unroll
            for (int j = 0; j < 4; j++) {
                int row = wn * 64 + j * 16 + la;
                b[j] = *reinterpret_cast<const bfrag*>(&Bs[row * 64 + (((kk * 4 + hi) ^ (la & 7)) * 8)]);
            }
#pragma unroll
            for (int i = 0; i < 4; i++)
#pragma unroll
                for (int j = 0; j < 4; j++)
                    acc[i][j] = __builtin_amdgcn_mfma_f32_16x16x32_bf16(a[i], b[j], acc[i][j], 0, 0, 0);
        }
    }

#pragma unroll
    for (int j = 0; j < 4; j++) {
        int col = wn * 64 + j * 16 + la;
        float bv = bias[col];
#pragma unroll
        for (int i = 0; i < 4; i++) {
            int rbase = bm + wm * 64 + i * 16 + hi * 4;
#pragma unroll
            for (int r = 0; r < 4; r++)
                C[(size_t)(rbase + r) * N + col] = f2bf(acc[i][j][r] + bv);
        }
    }
}

// ---------- fused LayerNorm + segment-mean + feature concat ----------
__global__ __launch_bounds__(512) void seg_ln_mean(const unsigned short* __restrict__ h,
                                                   const int* __restrict__ a_scope,
                                                   const float* __restrict__ g,
                                                   const float* __restrict__ b,
                                                   const float* __restrict__ feats,
                                                   unsigned short* __restrict__ mol, int n_mols) {
    __shared__ float part[8][256];
    int m = blockIdx.x, t = threadIdx.x;
    unsigned short* mrow = mol + (size_t)m * 512;
    if (m >= n_mols) {
        mrow[t] = 0;
        return;
    }
    int w = t >> 6, lane = t & 63;
    int start = a_scope[2 * m], size = a_scope[2 * m + 1];
    float4 gv = *reinterpret_cast<const float4*>(g + lane * 4);
    float4 bv = *reinterpret_cast<const float4*>(b + lane * 4);
    float a0 = 0.f, a1 = 0.f, a2 = 0.f, a3 = 0.f;
    for (int r = w; r < size; r += 8) {
        const unsigned short* hp = h + (size_t)(start + r) * 256 + lane * 4;
        ushort4 u = *reinterpret_cast<const ushort4*>(hp);
        float v0 = bf2f(u.x), v1 = bf2f(u.y), v2 = bf2f(u.z), v3 = bf2f(u.w);
        float s = v0 + v1 + v2 + v3;
        float q2 = v0 * v0 + v1 * v1 + v2 * v2 + v3 * v3;
#pragma unroll
        for (int off = 32; off; off >>= 1) {
            s += __shfl_xor(s, off);
            q2 += __shfl_xor(q2, off);
        }
        float mean = s * (1.f / 256.f);
        float var = q2 * (1.f / 256.f) - mean * mean;
        float rs = rsqrtf(var + 1e-5f);
        a0 += (v0 - mean) * rs * gv.x + bv.x;
        a1 += (v1 - mean) * rs * gv.y + bv.y;
        a2 += (v2 - mean) * rs * gv.z + bv.z;
        a3 += (v3 - mean) * rs * gv.w + bv.w;
    }
    part[w][lane * 4 + 0] = a0;
    part[w][lane * 4 + 1] = a1;
    part[w][lane * 4 + 2] = a2;
    part[w][lane * 4 + 3] = a3;
    __syncthreads();
    if (t < 256) {
        float sum = 0.f;
#pragma unroll
        for (int i = 0; i < 8; i++) sum += part[i][t];
        mrow[t] = f2bf(sum / (float)size);
    } else {
        int c = t - 256;
        float fv = (c < 200) ? feats[(size_t)m * 200 + c] : 0.f;
        mrow[256 + c] = f2bf(fv);
    }
}

// ---------- final tiny FFN layer ----------
__global__ void ffn2(const unsigned short* __restrict__ m1, const float* __restrict__ Wm2,
                     const float* __restrict__ bm2, float* __restrict__ out, int n_mols) {
    int wid = blockIdx.x * 4 + (threadIdx.x >> 6);
    if (wid >= n_mols) return;
    int lane = threadIdx.x & 63;
    float acc[12] = {};
    const unsigned short* row = m1 + (size_t)wid * 1024;
#pragma unroll 4
    for (int i = 0; i < 16; i++) {
        int k = i * 64 + lane;
        float v = bf2f(row[k]);
        const float* wr_ = Wm2 + (size_t)k * 12;
#pragma unroll
        for (int tsk = 0; tsk < 12; tsk++) acc[tsk] += v * wr_[tsk];
    }
#pragma unroll
    for (int tsk = 0; tsk < 12; tsk++) {
        float sv = acc[tsk];
#pragma unroll
        for (int off = 32; off; off >>= 1) sv += __shfl_xor(sv, off);
        if (lane == 0) out[(size_t)wid * 12 + tsk] = sv + bm2[tsk];
    }
}

// ---------- launch ----------
extern "C" void kernel_launch(void* const* d_in, const int* in_sizes, int n_in,
                              void* d_out, int out_size, void* d_ws, size_t ws_size,
                              hipStream_t stream) {
    const float* atom_output = (const float*)d_in[0];
    const float* f_atoms     = (const float*)d_in[1];
    const int*   a2a         = (const int*)d_in[2];
    const int*   a_scope     = (const int*)d_in[3];
    const float* feats       = (const float*)d_in[4];
    const float* W1  = (const float*)d_in[5];
    const float* b1  = (const float*)d_in[6];
    const float* W2  = (const float*)d_in[7];
    const float* b2  = (const float*)d_in[8];
    const float* ln_g = (const float*)d_in[9];
    const float* ln_b = (const float*)d_in[10];
    const float* Wm1 = (const float*)d_in[11];
    const float* bm1 = (const float*)d_in[12];
    const float* Wm2 = (const float*)d_in[13];
    const float* bm2 = (const float*)d_in[14];
    float* out = (float*)d_out;

    char* ws = (char*)d_ws;
    size_t off = 0;
    auto alloc = [&](size_t bytes) {
        void* p = ws + off;
        off += (bytes + 255) & ~(size_t)255;
        return p;
    };
    // r12 layout (~356 MB). abf aliases h1 (dead before gemm1 writes h1).
    unsigned short* h     = (unsigned short*)alloc((size_t)100096 * 256 * 2);    // 51.2 MB
    unsigned short* h1    = (unsigned short*)alloc((size_t)100096 * 1024 * 2);   // 205.0 MB
    unsigned short* xf    = (unsigned short*)alloc((size_t)100096 * 448 * 2);    // 89.7 MB
    unsigned short* mol   = (unsigned short*)alloc((size_t)2560 * 512 * 2);
    unsigned short* m1b   = (unsigned short*)alloc((size_t)2560 * 1024 * 2);
    unsigned short* W1bT  = (unsigned short*)alloc((size_t)1024 * 448 * 2);
    unsigned short* W2bT  = (unsigned short*)alloc((size_t)256 * 1024 * 2);
    unsigned short* Wm1bT = (unsigned short*)alloc((size_t)1024 * 512 * 2);
    unsigned short* abf   = h1;   // alias: consumed by gather2 before h1 is written

    // ONE prep dispatch: bf16 convert + all 3 weight transposes (saves 3 launch boundaries)
    prep<<<13716, dim3(32, 8), 0, stream>>>(atom_output, abf, W1, W1bT, W2, W2bT, Wm1, Wm1bT);

    gather2<<<25024, 256, 0, stream>>>(abf, f_atoms, a2a, xf, 100000);

    // h1 = relu(x @ W1 + b1) : M=100096 (391x256), N=1024, K=448 ; r12-verified kernel
    gemm256<1><<<391 * 8, 512, 0, stream>>>(xf, W1bT, b1, h1, 8, 1024, 448);
    // h = h1 @ W2 + b2 : M=100096 (782x128), N=256, K=1024 ; NB=1 -> h1 staged ONCE
    gemm2k<<<782, 512, 0, stream>>>(h1, W2bT, b2, h, 1024);

    seg_ln_mean<<<2560, 512, 0, stream>>>(h, a_scope, ln_g, ln_b, feats, mol, 2500);
    // m1 = relu(mol @ Wm1 + bm1) : M=2560 (10x256), N=1024, K=512
    gemm256<1><<<10 * 8, 512, 0, stream>>>(mol, Wm1bT, bm1, m1b, 8, 1024, 512);
    ffn2<<<625, 256, 0, stream>>>(m1b, Wm2, bm2, out, 2500);
}